// Round 4
// baseline (332.392 us; speedup 1.0000x reference)
//
#include <hip/hip_runtime.h>
#include <hip/hip_bf16.h>
#include <cstdint>
#include <cstddef>

#define B_ 2
#define S_ 2048
#define NH_ 16
#define NKV_ 4
#define HD_ 128
#define QDIM_ 2048
#define KVDIM_ 512
#define QKV_ 3072

typedef __attribute__((ext_vector_type(8))) short short8;
typedef __attribute__((ext_vector_type(4))) short bhalf4;   // short4 collides with HIP
typedef __attribute__((ext_vector_type(4))) float float4v;
typedef __attribute__((ext_vector_type(2))) float float2v;

__device__ __forceinline__ float bf2f(short u) {
  union { unsigned int i; float f; } v;
  v.i = ((unsigned int)(unsigned short)u) << 16;
  return v.f;
}
__device__ __forceinline__ short f2bf(float f) {
  union { float f; unsigned int i; } v; v.f = f;
  unsigned int x = v.i;
  x += 0x7fffu + ((x >> 16) & 1u);   // RNE
  return (short)(x >> 16);
}

#if __has_builtin(__builtin_amdgcn_exp2f)
__device__ __forceinline__ float exp2fast(float x) { return __builtin_amdgcn_exp2f(x); }
#else
__device__ __forceinline__ float exp2fast(float x) { return exp2f(x); }
#endif

// packed f32x2 -> bf16x2 (T12 recipe; no builtin on gfx950)
__device__ __forceinline__ unsigned int cvt_pk_bf16(float a, float b) {
  unsigned int r;
  asm("v_cvt_pk_bf16_f32 %0, %1, %2" : "=v"(r) : "v"(a), "v"(b));
  return r;
}

__device__ __forceinline__ void async_copy16(void* lds, const void* g) {
  __builtin_amdgcn_global_load_lds(
      (const __attribute__((address_space(1))) void*)g,
      (__attribute__((address_space(3))) void*)lds, 16, 0, 0);
}

// ---------------------------------------------------------------------------
// fp32 -> bf16 convert (HBM-bound). n8 = element count / 8.
// ---------------------------------------------------------------------------
__global__ void f32_to_bf16(const float* __restrict__ src, short* __restrict__ dst,
                            int n8) {
  int id = blockIdx.x * 256 + threadIdx.x;
  if (id >= n8) return;
  const float* f = src + (size_t)id * 8;
  float4v a = *(const float4v*)(f);
  float4v b = *(const float4v*)(f + 4);
  short8 r;
#pragma unroll
  for (int e = 0; e < 4; ++e) { r[e] = f2bf(a[e]); r[4 + e] = f2bf(b[e]); }
  *(short8*)(dst + (size_t)id * 8) = r;
}

// ---------------------------------------------------------------------------
// NT GEMM, pure bf16 operands (used for the output projection).
// ---------------------------------------------------------------------------
template <int N, int K, bool CF32>
__global__ __launch_bounds__(256)
void gemm_nt_bf16(const short* __restrict__ A, const short* __restrict__ Bm,
                  void* __restrict__ Cp) {
  __shared__ __align__(16) short sA[128 * 32];
  __shared__ __align__(16) short sB[128 * 32];
  const int tid = threadIdx.x;
  const int m0 = blockIdx.y * 128, n0 = blockIdx.x * 128;
  const int wave = tid >> 6, lane = tid & 63;
  const int wm = (wave & 1) << 6, wn = (wave >> 1) << 6;
  const int lm = lane & 15, kg = lane >> 4;

  float4v acc[4][4];
#pragma unroll
  for (int i = 0; i < 4; ++i)
#pragma unroll
    for (int j = 0; j < 4; ++j)
      acc[i][j] = (float4v){0.f, 0.f, 0.f, 0.f};

  const int r0 = tid >> 2, c0 = tid & 3;
  const short* gA0 = A + (size_t)(m0 + r0) * K + c0 * 8;
  const short* gA1 = gA0 + (size_t)64 * K;
  const short* gB0 = Bm + (size_t)(n0 + r0) * K + c0 * 8;
  const short* gB1 = gB0 + (size_t)64 * K;
  short* lA0 = sA + tid * 8;
  short* lA1 = sA + 2048 + tid * 8;
  short* lB0 = sB + tid * 8;
  short* lB1 = sB + 2048 + tid * 8;

  for (int k0 = 0; k0 < K; k0 += 32) {
    async_copy16(lA0, gA0 + k0);
    async_copy16(lA1, gA1 + k0);
    async_copy16(lB0, gB0 + k0);
    async_copy16(lB1, gB1 + k0);
    __syncthreads();

    short8 a[4], b[4];
#pragma unroll
    for (int i = 0; i < 4; ++i)
      a[i] = *(const short8*)(sA + (wm + i * 16 + lm) * 32 + kg * 8);
#pragma unroll
    for (int j = 0; j < 4; ++j)
      b[j] = *(const short8*)(sB + (wn + j * 16 + lm) * 32 + kg * 8);
#pragma unroll
    for (int i = 0; i < 4; ++i)
#pragma unroll
      for (int j = 0; j < 4; ++j)
        acc[i][j] = __builtin_amdgcn_mfma_f32_16x16x32_bf16(a[i], b[j], acc[i][j], 0, 0, 0);
    __syncthreads();
  }

#pragma unroll
  for (int i = 0; i < 4; ++i) {
    const int rb = m0 + wm + i * 16 + kg * 4;
#pragma unroll
    for (int j = 0; j < 4; ++j) {
      const int cc = n0 + wn + j * 16 + lm;
#pragma unroll
      for (int r = 0; r < 4; ++r) {
        if constexpr (CF32)
          ((float*)Cp)[(size_t)(rb + r) * N + cc] = acc[i][j][r];
        else
          ((short*)Cp)[(size_t)(rb + r) * N + cc] = f2bf(acc[i][j][r]);
      }
    }
  }
}

// ---------------------------------------------------------------------------
// QKV GEMM with fused RoPE + split epilogue, v2: LDS-staged coalesced stores.
// Each n-block of 128 channels = exactly one head, so the 128x128 tile maps
// to 128 contiguous 256B rows of Qr/Kr. The rotated tile is staged in LDS
// (ROWP=136 pad: 16B-aligned rows, 2-way banks = free) then stored as
// vectorized short8 rows. V blocks stage TRANSPOSED ([d][token]) and store
// rows directly into Vt [b][kvh][d][s] — transpose_v kernel eliminated.
// Rope pairing: channel cc^1 lives in lane^1 -> shfl_xor(v,1). Q pre-scaled
// by (1/sqrt(HD))*log2(e) for exp2-domain softmax. All branching is
// block-uniform (head type is a function of blockIdx.x only).
// ---------------------------------------------------------------------------
__global__ __launch_bounds__(256)
void gemm_qkv_rope(const short* __restrict__ A, const short* __restrict__ Bm,
                   const float* __restrict__ freqs, short* __restrict__ Qr,
                   short* __restrict__ Kr, short* __restrict__ Vt) {
  constexpr int K = 2048;
  constexpr int ROWP = 136;
  __shared__ __align__(16) short smem[128 * ROWP];   // 34.8 KB; k-loop uses 16 KB
  short* sA = smem;
  short* sB = smem + 4096;
  const int tid = threadIdx.x;
  const int m0 = blockIdx.y * 128, n0 = blockIdx.x * 128;
  const int wave = tid >> 6, lane = tid & 63;
  const int wm = (wave & 1) << 6, wn = (wave >> 1) << 6;
  const int lm = lane & 15, kg = lane >> 4;

  float4v acc[4][4];
#pragma unroll
  for (int i = 0; i < 4; ++i)
#pragma unroll
    for (int j = 0; j < 4; ++j)
      acc[i][j] = (float4v){0.f, 0.f, 0.f, 0.f};

  const int r0 = tid >> 2, c0 = tid & 3;
  const short* gA0 = A + (size_t)(m0 + r0) * K + c0 * 8;
  const short* gA1 = gA0 + (size_t)64 * K;
  const short* gB0 = Bm + (size_t)(n0 + r0) * K + c0 * 8;
  const short* gB1 = gB0 + (size_t)64 * K;
  short* lA0 = sA + tid * 8;
  short* lA1 = sA + 2048 + tid * 8;
  short* lB0 = sB + tid * 8;
  short* lB1 = sB + 2048 + tid * 8;

  for (int k0 = 0; k0 < K; k0 += 32) {
    async_copy16(lA0, gA0 + k0);
    async_copy16(lA1, gA1 + k0);
    async_copy16(lB0, gB0 + k0);
    async_copy16(lB1, gB1 + k0);
    __syncthreads();

    short8 a[4], b[4];
#pragma unroll
    for (int i = 0; i < 4; ++i)
      a[i] = *(const short8*)(sA + (wm + i * 16 + lm) * 32 + kg * 8);
#pragma unroll
    for (int j = 0; j < 4; ++j)
      b[j] = *(const short8*)(sB + (wn + j * 16 + lm) * 32 + kg * 8);
#pragma unroll
    for (int i = 0; i < 4; ++i)
#pragma unroll
      for (int j = 0; j < 4; ++j)
        acc[i][j] = __builtin_amdgcn_mfma_f32_16x16x32_bf16(a[i], b[j], acc[i][j], 0, 0, 0);
    __syncthreads();
  }
  // (last loop iteration ends with a barrier; sA/sB are dead -> reuse as tile)

  const int nb = blockIdx.x;          // 0..15 Q-heads, 16..19 K-heads, 20..23 V
  const bool isV = (nb >= 20);
  const int s0 = m0 & (S_ - 1);
  const int bq = m0 >> 11;            // tiles never straddle the batch boundary

  if (!isV) {
    const float sc = (nb < 16) ? 0.12751744543795287f : 1.f;  // Q: rsqrt(128)*log2e
#pragma unroll
    for (int i = 0; i < 4; ++i) {
#pragma unroll
      for (int j = 0; j < 4; ++j) {
        const int d = wn + j * 16 + lm;        // channel within head, 0..127
#pragma unroll
        for (int r = 0; r < 4; ++r) {
          const int trow = wm + i * 16 + kg * 4 + r;   // local token, 0..127
          const float v = acc[i][j][r];
          const float p = __shfl_xor(v, 1, 64);        // partner channel d^1
          const float2v f =
              *(const float2v*)(freqs + (size_t)(s0 + trow) * HD_ + (d & ~1));
          const float outv = (d & 1) ? (p * f[0] + v * f[1])
                                     : (v * f[1] - p * f[0]);
          smem[trow * ROWP + d] = f2bf(outv * sc);
        }
      }
    }
    __syncthreads();
    short* gout = (nb < 16)
        ? Qr + ((size_t)(bq * NH_ + nb) * S_ + s0) * HD_
        : Kr + ((size_t)(bq * NKV_ + (nb - 16)) * S_ + s0) * HD_;
#pragma unroll
    for (int it = 0; it < 8; ++it) {
      const int ch = tid + 256 * it, row = ch >> 4, cn = ch & 15;
      *(short8*)(gout + (size_t)row * HD_ + cn * 8) =
          *(const short8*)(smem + row * ROWP + cn * 8);
    }
  } else {
    // stage transposed: smem[d][token]
#pragma unroll
    for (int i = 0; i < 4; ++i)
#pragma unroll
      for (int j = 0; j < 4; ++j)
#pragma unroll
        for (int r = 0; r < 4; ++r)
          smem[(wn + j * 16 + lm) * ROWP + (wm + i * 16 + kg * 4 + r)] =
              f2bf(acc[i][j][r]);
    __syncthreads();
    short* gv = Vt + (size_t)(bq * NKV_ + (nb - 20)) * HD_ * S_;
#pragma unroll
    for (int it = 0; it < 8; ++it) {
      const int ch = tid + 256 * it, d = ch >> 4, cn = ch & 15;
      *(short8*)(gv + (size_t)d * S_ + s0 + cn * 8) =
          *(const short8*)(smem + d * ROWP + cn * 8);
    }
  }
}

// ---------------------------------------------------------------------------
// Flash attention v8: global_load_lds staging, 2-barrier step, TK=128 —
// two 64-key tiles' worth of work per barrier pair (halves per-key fixed
// cost: barrier drains, shfl reduces, O-rescale passes, dep-chain latency).
// LDS 64 KB -> 2 blocks/CU. launch_bounds(256,2) -> 256-VGPR budget.
// ---------------------------------------------------------------------------
#define TK 128

__global__ __launch_bounds__(256, 2)
void attn_causal(const short* __restrict__ Q, const short* __restrict__ K,
                 const short* __restrict__ Vt, short* __restrict__ O) {
  const int bh = blockIdx.x;                 // 0..31
  const int qt = 31 - (int)blockIdx.y;       // longest blocks dispatch first
  const int b = bh >> 4, h = bh & 15;
  const int kvh = h >> 2;
  const int tid = threadIdx.x, wave = tid >> 6, lane = tid & 63;
  const int lm = lane & 15, kg = lane >> 4;

  __shared__ __align__(16) short sK[TK * HD_];    // 32 KB, swizzled
  __shared__ __align__(16) short sVt[HD_ * TK];   // 32 KB, swizzled

  const short* Qb = Q + (size_t)(b * NH_ + h) * S_ * HD_;
  const short* Kb = K + (size_t)(b * NKV_ + kvh) * S_ * HD_;
  const short* Vtb = Vt + (size_t)(b * NKV_ + kvh) * S_ * HD_;

  auto stageK = [&](int k0) {
#pragma unroll
    for (int c = 0; c < 8; ++c) {
      int ch = tid + 256 * c;
      int row = ch >> 4, kc = ch & 15;
      async_copy16(sK + ch * 8,
                   Kb + (size_t)(k0 + row) * HD_ + (kc ^ (row & 7)) * 8);
    }
  };
  auto stageV = [&](int k0) {
#pragma unroll
    for (int c = 0; c < 8; ++c) {
      int ch = tid + 256 * c;
      int row = ch >> 4, kc = ch & 15;   // row = d (0..127), 16 chunks of 8 keys
      async_copy16(sVt + ch * 8,
                   Vtb + (size_t)row * S_ + k0 + (kc ^ (row & 7)) * 8);
    }
  };

  const int qglob = qt * 64 + wave * 16 + lm;   // this lane's q row
  short8 qf[4];
#pragma unroll
  for (int kk = 0; kk < 4; ++kk)
    qf[kk] = *(const short8*)(Qb + (size_t)qglob * HD_ + kk * 32 + kg * 8);

  float mcur = -1e9f, lcur = 0.f;
  float4v o[8];
#pragma unroll
  for (int df = 0; df < 8; ++df) o[df] = (float4v){0.f, 0.f, 0.f, 0.f};

  stageK(0);
  const int nst = (qt + 2) >> 1;   // ceil((qt*64+64)/128)
  for (int s = 0; s < nst; ++s) {
    const int k0 = s * TK;
    const bool last = (s == nst - 1);

    __syncthreads();           // B1: K[s] landed; all waves done PV[s-1]
    stageV(k0);                // V[s]; lands by B2

    // S^T = K * Q^T  (128 keys x 16 q, 32 MFMAs)
    float4v sfT[8];
#pragma unroll
    for (int mj = 0; mj < 8; ++mj) sfT[mj] = (float4v){0.f, 0.f, 0.f, 0.f};
    __builtin_amdgcn_s_setprio(1);
#pragma unroll
    for (int kk = 0; kk < 4; ++kk) {
      int kd = kk * 4 + kg;
#pragma unroll
      for (int mj = 0; mj < 8; ++mj) {
        int row = mj * 16 + lm;
        short8 af = *(const short8*)(sK + row * HD_ + (kd ^ (row & 7)) * 8);
        sfT[mj] = __builtin_amdgcn_mfma_f32_16x16x32_bf16(af, qf[kk], sfT[mj], 0, 0, 0);
      }
    }
    __builtin_amdgcn_s_setprio(0);

    if (last) {   // causal mask (covers diag tile and even-qt overhang)
#pragma unroll
      for (int mj = 0; mj < 8; ++mj)
#pragma unroll
        for (int r = 0; r < 4; ++r) {
          int kcol = k0 + mj * 16 + kg * 4 + r;
          sfT[mj][r] = (kcol <= qglob) ? sfT[mj][r] : -3e38f;
        }
    }

    // online softmax (exp2 domain), defer-max with THR=4 (P bounded by 16)
    float mx = -3e38f;
#pragma unroll
    for (int mj = 0; mj < 8; ++mj)
#pragma unroll
      for (int r = 0; r < 4; ++r) mx = fmaxf(mx, sfT[mj][r]);
    mx = fmaxf(mx, __shfl_xor(mx, 16, 64));
    mx = fmaxf(mx, __shfl_xor(mx, 32, 64));
    const bool need = (mx > mcur + 4.f);
    const float mnew = fmaxf(mcur, mx);
    const float alpha = need ? exp2fast(mcur - mnew) : 1.f;
    const float m_use = need ? mnew : mcur;
    float rs = 0.f;
    bhalf4 pb[8];   // P^T B-frags for x16 MFMA: B[n=q][k=t*16+kg*4+r]
#pragma unroll
    for (int t = 0; t < 8; ++t) {
      float e0 = exp2fast(sfT[t][0] - m_use);
      float e1 = exp2fast(sfT[t][1] - m_use);
      float e2 = exp2fast(sfT[t][2] - m_use);
      float e3 = exp2fast(sfT[t][3] - m_use);
      rs += (e0 + e1) + (e2 + e3);
      union { unsigned int u[2]; bhalf4 v; } pk;
      pk.u[0] = cvt_pk_bf16(e0, e1);
      pk.u[1] = cvt_pk_bf16(e2, e3);
      pb[t] = pk.v;
    }
    rs += __shfl_xor(rs, 16, 64);
    rs += __shfl_xor(rs, 32, 64);
    mcur = m_use;
    lcur = lcur * alpha + rs;

    __syncthreads();           // B2: V[s] landed; all waves done QK reads of sK
    if (!last) stageK(k0 + TK);   // K[s+1]; lands by next B1

    if (__any(need)) {
#pragma unroll
      for (int df = 0; df < 8; ++df)
#pragma unroll
        for (int r = 0; r < 4; ++r) o[df][r] *= alpha;
    }

    // O^T += V^T * P^T  (x16 MFMA, 8 k-chunks of 16)
    __builtin_amdgcn_s_setprio(1);
#pragma unroll
    for (int t = 0; t < 8; ++t) {
      int kc = t * 2 + (kg >> 1);   // 16B chunk 0..15 within the 256B row
#pragma unroll
      for (int df = 0; df < 8; ++df) {
        int row = df * 16 + lm;
        bhalf4 va = *(const bhalf4*)(sVt + row * TK + (kc ^ (row & 7)) * 8 +
                                     (kg & 1) * 4);
        o[df] = __builtin_amdgcn_mfma_f32_16x16x16bf16_1k(va, pb[t], o[df], 0, 0, 0);
      }
    }
    __builtin_amdgcn_s_setprio(0);
  }

  // epilogue: lane owns q-row qglob, d = df*16 + kg*4 + r -> contiguous 8B
  const float inv = 1.f / lcur;
  const size_t rowoff = (size_t)(b * S_ + qglob) * QDIM_ + h * HD_ + kg * 4;
#pragma unroll
  for (int df = 0; df < 8; ++df) {
    bhalf4 w;
    w[0] = f2bf(o[df][0] * inv);
    w[1] = f2bf(o[df][1] * inv);
    w[2] = f2bf(o[df][2] * inv);
    w[3] = f2bf(o[df][3] * inv);
    *(bhalf4*)(O + rowoff + df * 16) = w;
  }
}

// ---------------------------------------------------------------------------
extern "C" void kernel_launch(void* const* d_in, const int* in_sizes, int n_in,
                              void* d_out, int out_size, void* d_ws, size_t ws_size,
                              hipStream_t stream) {
  const float* x     = (const float*)d_in[0];  // [B,S,D] fp32
  const float* freqs = (const float*)d_in[1];  // [S,HD] fp32
  const float* Wqkv  = (const float*)d_in[2];  // [3072,2048] fp32
  const float* Wo    = (const float*)d_in[3];  // [2048,2048] fp32
  float* out = (float*)d_out;                  // [B,S,D] fp32

  short* ws     = (short*)d_ws;
  short* xb     = ws;                                    // 4096*2048
  short* Wob    = ws;                                    // 2048*2048 (alias xb;
                                                         //  written after QKV GEMM)
  short* Wqkvb  = ws + (size_t)4096 * 2048;              // 3072*2048
  short* attn   = Wqkvb + (size_t)QKV_ * 2048;           // 4096*2048
  short* Qr     = attn + (size_t)4096 * 2048;
  short* Kr     = Qr + (size_t)B_ * NH_ * S_ * HD_;
  short* Vtg    = Kr + (size_t)B_ * NKV_ * S_ * HD_;
  // total ~37.8M shorts = 75.5 MB

  f32_to_bf16<<<(4096 * 2048 / 8) / 256, 256, 0, stream>>>(x, xb, 4096 * 2048 / 8);
  f32_to_bf16<<<(QKV_ * 2048 / 8) / 256, 256, 0, stream>>>(Wqkv, Wqkvb, QKV_ * 2048 / 8);
  gemm_qkv_rope<<<dim3(QKV_ / 128, 4096 / 128), 256, 0, stream>>>(
      xb, Wqkvb, freqs, Qr, Kr, Vtg);
  f32_to_bf16<<<(2048 * 2048 / 8) / 256, 256, 0, stream>>>(Wo, Wob, 2048 * 2048 / 8);
  attn_causal<<<dim3(32, 32), 256, 0, stream>>>(Qr, Kr, Vtg, attn);
  gemm_nt_bf16<2048, 2048, true>
      <<<dim3(2048 / 128, 4096 / 128), 256, 0, stream>>>(attn, Wob, out);
}

// Round 5
// 309.606 us; speedup vs baseline: 1.0736x; 1.0736x over previous
//
#include <hip/hip_runtime.h>
#include <hip/hip_bf16.h>
#include <cstdint>
#include <cstddef>

#define B_ 2
#define S_ 2048
#define NH_ 16
#define NKV_ 4
#define HD_ 128
#define QDIM_ 2048
#define KVDIM_ 512
#define QKV_ 3072

typedef __attribute__((ext_vector_type(8))) short short8;
typedef __attribute__((ext_vector_type(4))) short bhalf4;   // short4 collides with HIP
typedef __attribute__((ext_vector_type(4))) float float4v;

__device__ __forceinline__ float bf2f(short u) {
  union { unsigned int i; float f; } v;
  v.i = ((unsigned int)(unsigned short)u) << 16;
  return v.f;
}
__device__ __forceinline__ short f2bf(float f) {
  union { float f; unsigned int i; } v; v.f = f;
  unsigned int x = v.i;
  x += 0x7fffu + ((x >> 16) & 1u);   // RNE
  return (short)(x >> 16);
}

#if __has_builtin(__builtin_amdgcn_exp2f)
__device__ __forceinline__ float exp2fast(float x) { return __builtin_amdgcn_exp2f(x); }
#else
__device__ __forceinline__ float exp2fast(float x) { return exp2f(x); }
#endif

// packed f32x2 -> bf16x2 (T12 recipe; no builtin on gfx950)
__device__ __forceinline__ unsigned int cvt_pk_bf16(float a, float b) {
  unsigned int r;
  asm("v_cvt_pk_bf16_f32 %0, %1, %2" : "=v"(r) : "v"(a), "v"(b));
  return r;
}

__device__ __forceinline__ void async_copy16(void* lds, const void* g) {
  __builtin_amdgcn_global_load_lds(
      (const __attribute__((address_space(1))) void*)g,
      (__attribute__((address_space(3))) void*)lds, 16, 0, 0);
}

// ---------------------------------------------------------------------------
// fp32 -> bf16 converts (HBM-bound). Two-range fused variant saves a launch.
// Range sizes are multiples of 256*8 so the branch is block-uniform.
// ---------------------------------------------------------------------------
__device__ __forceinline__ void cvt8(const float* f, short* d) {
  float4v a = *(const float4v*)(f);
  float4v b = *(const float4v*)(f + 4);
  short8 r;
#pragma unroll
  for (int e = 0; e < 4; ++e) { r[e] = f2bf(a[e]); r[4 + e] = f2bf(b[e]); }
  *(short8*)d = r;
}

__global__ void f32_to_bf16(const float* __restrict__ src, short* __restrict__ dst,
                            int n8) {
  int id = blockIdx.x * 256 + threadIdx.x;
  if (id >= n8) return;
  cvt8(src + (size_t)id * 8, dst + (size_t)id * 8);
}

__global__ void f32_to_bf16_2(const float* __restrict__ s0, short* __restrict__ d0,
                              int n0_8, const float* __restrict__ s1,
                              short* __restrict__ d1) {
  int id = blockIdx.x * 256 + threadIdx.x;
  if (id < n0_8) {
    cvt8(s0 + (size_t)id * 8, d0 + (size_t)id * 8);
  } else {
    int j = id - n0_8;
    cvt8(s1 + (size_t)j * 8, d1 + (size_t)j * 8);
  }
}

// ---------------------------------------------------------------------------
// NT GEMM, pure bf16 operands (m97 structure; verified).
// ---------------------------------------------------------------------------
template <int N, int K, bool CF32>
__global__ __launch_bounds__(256)
void gemm_nt_bf16(const short* __restrict__ A, const short* __restrict__ Bm,
                  void* __restrict__ Cp) {
  __shared__ __align__(16) short sA[128 * 32];
  __shared__ __align__(16) short sB[128 * 32];
  const int tid = threadIdx.x;
  const int m0 = blockIdx.y * 128, n0 = blockIdx.x * 128;
  const int wave = tid >> 6, lane = tid & 63;
  const int wm = (wave & 1) << 6, wn = (wave >> 1) << 6;
  const int lm = lane & 15, kg = lane >> 4;

  float4v acc[4][4];
#pragma unroll
  for (int i = 0; i < 4; ++i)
#pragma unroll
    for (int j = 0; j < 4; ++j)
      acc[i][j] = (float4v){0.f, 0.f, 0.f, 0.f};

  const int r0 = tid >> 2, c0 = tid & 3;
  const short* gA0 = A + (size_t)(m0 + r0) * K + c0 * 8;
  const short* gA1 = gA0 + (size_t)64 * K;
  const short* gB0 = Bm + (size_t)(n0 + r0) * K + c0 * 8;
  const short* gB1 = gB0 + (size_t)64 * K;
  short* lA0 = sA + tid * 8;
  short* lA1 = sA + 2048 + tid * 8;
  short* lB0 = sB + tid * 8;
  short* lB1 = sB + 2048 + tid * 8;

  for (int k0 = 0; k0 < K; k0 += 32) {
    async_copy16(lA0, gA0 + k0);
    async_copy16(lA1, gA1 + k0);
    async_copy16(lB0, gB0 + k0);
    async_copy16(lB1, gB1 + k0);
    __syncthreads();

    short8 a[4], b[4];
#pragma unroll
    for (int i = 0; i < 4; ++i)
      a[i] = *(const short8*)(sA + (wm + i * 16 + lm) * 32 + kg * 8);
#pragma unroll
    for (int j = 0; j < 4; ++j)
      b[j] = *(const short8*)(sB + (wn + j * 16 + lm) * 32 + kg * 8);
#pragma unroll
    for (int i = 0; i < 4; ++i)
#pragma unroll
      for (int j = 0; j < 4; ++j)
        acc[i][j] = __builtin_amdgcn_mfma_f32_16x16x32_bf16(a[i], b[j], acc[i][j], 0, 0, 0);
    __syncthreads();
  }

#pragma unroll
  for (int i = 0; i < 4; ++i) {
    const int rb = m0 + wm + i * 16 + kg * 4;
#pragma unroll
    for (int j = 0; j < 4; ++j) {
      const int cc = n0 + wn + j * 16 + lm;
#pragma unroll
      for (int r = 0; r < 4; ++r) {
        if constexpr (CF32)
          ((float*)Cp)[(size_t)(rb + r) * N + cc] = acc[i][j][r];
        else
          ((short*)Cp)[(size_t)(rb + r) * N + cc] = f2bf(acc[i][j][r]);
      }
    }
  }
}

// ---------------------------------------------------------------------------
// RoPE + split/layout; Q pre-scaled by (1/sqrt(HD)) * log2(e) so attention
// softmax can run in exp2 domain (hardware v_exp_f32, no per-element mul).
// ---------------------------------------------------------------------------
__global__ void rope_split(const short* __restrict__ xqkv, const float* __restrict__ freqs,
                           short* __restrict__ Qr, short* __restrict__ Kr,
                           short* __restrict__ Vv) {
  const int id = blockIdx.x * 256 + threadIdx.x;
  const int i = id / (QKV_ / 8);   // token 0..4095
  const int c8 = id % (QKV_ / 8);
  const int col = c8 * 8;
  const int b = i >> 11, s = i & (S_ - 1);
  short8 xv = *(const short8*)(xqkv + (size_t)i * QKV_ + col);
  if (col < QDIM_ + KVDIM_) {
    int d;
    short* dst;
    float sc;
    if (col < QDIM_) {
      int hh = col >> 7; d = col & 127;
      dst = Qr + ((size_t)(b * NH_ + hh) * S_ + s) * HD_ + d;
      sc = 0.12751744543795287f;   // (1/sqrt(128)) * log2(e)
    } else {
      int cc = col - QDIM_;
      int hh = cc >> 7; d = cc & 127;
      dst = Kr + ((size_t)(b * NKV_ + hh) * S_ + s) * HD_ + d;
      sc = 1.0f;
    }
    const float* fp = freqs + (size_t)s * HD_ + d;
    float4v fa = *(const float4v*)(fp);
    float4v fb = *(const float4v*)(fp + 4);
    float ff[8] = {fa[0], fa[1], fa[2], fa[3], fb[0], fb[1], fb[2], fb[3]};
    short8 ov;
#pragma unroll
    for (int pp = 0; pp < 4; ++pp) {
      float t0 = bf2f(xv[2 * pp]), t1 = bf2f(xv[2 * pp + 1]);
      float f0 = ff[2 * pp], f1 = ff[2 * pp + 1];
      ov[2 * pp]     = f2bf((t0 * f1 - t1 * f0) * sc);
      ov[2 * pp + 1] = f2bf((t0 * f0 + t1 * f1) * sc);
    }
    *(short8*)dst = ov;
  } else {
    int cc = col - QDIM_ - KVDIM_;
    int hh = cc >> 7, d = cc & 127;
    *(short8*)(Vv + ((size_t)(b * NKV_ + hh) * S_ + s) * HD_ + d) = xv;
  }
}

// ---------------------------------------------------------------------------
// V transpose: Vv [b][kvh][s][d] -> Vt [b][kvh][d][s]. LDS-tiled 64x64.
// ---------------------------------------------------------------------------
__global__ void transpose_v(const short* __restrict__ Vv, short* __restrict__ Vt) {
  __shared__ short t[64][72];
  const int s0 = blockIdx.x * 64, d0 = blockIdx.y * 64;
  const short* src = Vv + (size_t)blockIdx.z * S_ * HD_;
  short* dst = Vt + (size_t)blockIdx.z * S_ * HD_;
  const int tid = threadIdx.x;
#pragma unroll
  for (int c = 0; c < 2; ++c) {
    int ch = tid + 256 * c;
    int row = ch >> 3, kc = ch & 7;
    *(short8*)(&t[row][kc * 8]) =
        *(const short8*)(src + (size_t)(s0 + row) * HD_ + d0 + kc * 8);
  }
  __syncthreads();
#pragma unroll
  for (int c = 0; c < 2; ++c) {
    int ch = tid + 256 * c;
    int drow = ch >> 3, sc = ch & 7;
    short8 w;
#pragma unroll
    for (int j = 0; j < 8; ++j) w[j] = t[sc * 8 + j][drow];
    *(short8*)(dst + (size_t)(d0 + drow) * S_ + s0 + sc * 8) = w;
  }
}

// ---------------------------------------------------------------------------
// Flash attention v8: global_load_lds staging, 2-barrier step, TK=128 —
// two 64-key tiles' worth of work per barrier pair (halves per-key fixed
// cost: barrier drains, shfl reduces, O-rescale passes, dep-chain latency).
// LDS 64 KB -> 2 blocks/CU. launch_bounds(256,2) -> 256-VGPR budget.
// ---------------------------------------------------------------------------
#define TK 128

__global__ __launch_bounds__(256, 2)
void attn_causal(const short* __restrict__ Q, const short* __restrict__ K,
                 const short* __restrict__ Vt, short* __restrict__ O) {
  const int bh = blockIdx.x;                 // 0..31
  const int qt = 31 - (int)blockIdx.y;       // longest blocks dispatch first
  const int b = bh >> 4, h = bh & 15;
  const int kvh = h >> 2;
  const int tid = threadIdx.x, wave = tid >> 6, lane = tid & 63;
  const int lm = lane & 15, kg = lane >> 4;

  __shared__ __align__(16) short sK[TK * HD_];    // 32 KB, swizzled
  __shared__ __align__(16) short sVt[HD_ * TK];   // 32 KB, swizzled

  const short* Qb = Q + (size_t)(b * NH_ + h) * S_ * HD_;
  const short* Kb = K + (size_t)(b * NKV_ + kvh) * S_ * HD_;
  const short* Vtb = Vt + (size_t)(b * NKV_ + kvh) * S_ * HD_;

  auto stageK = [&](int k0) {
#pragma unroll
    for (int c = 0; c < 8; ++c) {
      int ch = tid + 256 * c;
      int row = ch >> 4, kc = ch & 15;
      async_copy16(sK + ch * 8,
                   Kb + (size_t)(k0 + row) * HD_ + (kc ^ (row & 7)) * 8);
    }
  };
  auto stageV = [&](int k0) {
#pragma unroll
    for (int c = 0; c < 8; ++c) {
      int ch = tid + 256 * c;
      int row = ch >> 4, kc = ch & 15;   // row = d (0..127), 16 chunks of 8 keys
      async_copy16(sVt + ch * 8,
                   Vtb + (size_t)row * S_ + k0 + (kc ^ (row & 7)) * 8);
    }
  };

  const int qglob = qt * 64 + wave * 16 + lm;   // this lane's q row
  short8 qf[4];
#pragma unroll
  for (int kk = 0; kk < 4; ++kk)
    qf[kk] = *(const short8*)(Qb + (size_t)qglob * HD_ + kk * 32 + kg * 8);

  float mcur = -1e9f, lcur = 0.f;
  float4v o[8];
#pragma unroll
  for (int df = 0; df < 8; ++df) o[df] = (float4v){0.f, 0.f, 0.f, 0.f};

  stageK(0);
  const int nst = (qt + 2) >> 1;   // ceil((qt*64+64)/128)
  for (int s = 0; s < nst; ++s) {
    const int k0 = s * TK;
    const bool last = (s == nst - 1);

    __syncthreads();           // B1: K[s] landed; all waves done PV[s-1]
    stageV(k0);                // V[s]; lands by B2

    // S^T = K * Q^T  (128 keys x 16 q, 32 MFMAs)
    float4v sfT[8];
#pragma unroll
    for (int mj = 0; mj < 8; ++mj) sfT[mj] = (float4v){0.f, 0.f, 0.f, 0.f};
    __builtin_amdgcn_s_setprio(1);
#pragma unroll
    for (int kk = 0; kk < 4; ++kk) {
      int kd = kk * 4 + kg;
#pragma unroll
      for (int mj = 0; mj < 8; ++mj) {
        int row = mj * 16 + lm;
        short8 af = *(const short8*)(sK + row * HD_ + (kd ^ (row & 7)) * 8);
        sfT[mj] = __builtin_amdgcn_mfma_f32_16x16x32_bf16(af, qf[kk], sfT[mj], 0, 0, 0);
      }
    }
    __builtin_amdgcn_s_setprio(0);

    if (last) {   // causal mask (covers diag tile and even-qt overhang)
#pragma unroll
      for (int mj = 0; mj < 8; ++mj)
#pragma unroll
        for (int r = 0; r < 4; ++r) {
          int kcol = k0 + mj * 16 + kg * 4 + r;
          sfT[mj][r] = (kcol <= qglob) ? sfT[mj][r] : -3e38f;
        }
    }

    // online softmax (exp2 domain), defer-max with THR=4 (P bounded by 16)
    float mx = -3e38f;
#pragma unroll
    for (int mj = 0; mj < 8; ++mj)
#pragma unroll
      for (int r = 0; r < 4; ++r) mx = fmaxf(mx, sfT[mj][r]);
    mx = fmaxf(mx, __shfl_xor(mx, 16, 64));
    mx = fmaxf(mx, __shfl_xor(mx, 32, 64));
    const bool need = (mx > mcur + 4.f);
    const float mnew = fmaxf(mcur, mx);
    const float alpha = need ? exp2fast(mcur - mnew) : 1.f;
    const float m_use = need ? mnew : mcur;
    float rs = 0.f;
    bhalf4 pb[8];   // P^T B-frags for x16 MFMA: B[n=q][k=t*16+kg*4+r]
#pragma unroll
    for (int t = 0; t < 8; ++t) {
      float e0 = exp2fast(sfT[t][0] - m_use);
      float e1 = exp2fast(sfT[t][1] - m_use);
      float e2 = exp2fast(sfT[t][2] - m_use);
      float e3 = exp2fast(sfT[t][3] - m_use);
      rs += (e0 + e1) + (e2 + e3);
      union { unsigned int u[2]; bhalf4 v; } pk;
      pk.u[0] = cvt_pk_bf16(e0, e1);
      pk.u[1] = cvt_pk_bf16(e2, e3);
      pb[t] = pk.v;
    }
    rs += __shfl_xor(rs, 16, 64);
    rs += __shfl_xor(rs, 32, 64);
    mcur = m_use;
    lcur = lcur * alpha + rs;

    __syncthreads();           // B2: V[s] landed; all waves done QK reads of sK
    if (!last) stageK(k0 + TK);   // K[s+1]; lands by next B1

    if (__any(need)) {
#pragma unroll
      for (int df = 0; df < 8; ++df)
#pragma unroll
        for (int r = 0; r < 4; ++r) o[df][r] *= alpha;
    }

    // O^T += V^T * P^T  (x16 MFMA, 8 k-chunks of 16)
    __builtin_amdgcn_s_setprio(1);
#pragma unroll
    for (int t = 0; t < 8; ++t) {
      int kc = t * 2 + (kg >> 1);   // 16B chunk 0..15 within the 256B row
#pragma unroll
      for (int df = 0; df < 8; ++df) {
        int row = df * 16 + lm;
        bhalf4 va = *(const bhalf4*)(sVt + row * TK + (kc ^ (row & 7)) * 8 +
                                     (kg & 1) * 4);
        o[df] = __builtin_amdgcn_mfma_f32_16x16x16bf16_1k(va, pb[t], o[df], 0, 0, 0);
      }
    }
    __builtin_amdgcn_s_setprio(0);
  }

  // epilogue: lane owns q-row qglob, d = df*16 + kg*4 + r -> contiguous 8B
  const float inv = 1.f / lcur;
  const size_t rowoff = (size_t)(b * S_ + qglob) * QDIM_ + h * HD_ + kg * 4;
#pragma unroll
  for (int df = 0; df < 8; ++df) {
    bhalf4 w;
    w[0] = f2bf(o[df][0] * inv);
    w[1] = f2bf(o[df][1] * inv);
    w[2] = f2bf(o[df][2] * inv);
    w[3] = f2bf(o[df][3] * inv);
    *(bhalf4*)(O + rowoff + df * 16) = w;
  }
}

// ---------------------------------------------------------------------------
extern "C" void kernel_launch(void* const* d_in, const int* in_sizes, int n_in,
                              void* d_out, int out_size, void* d_ws, size_t ws_size,
                              hipStream_t stream) {
  const float* x     = (const float*)d_in[0];  // [B,S,D] fp32
  const float* freqs = (const float*)d_in[1];  // [S,HD] fp32
  const float* Wqkv  = (const float*)d_in[2];  // [3072,2048] fp32
  const float* Wo    = (const float*)d_in[3];  // [2048,2048] fp32
  float* out = (float*)d_out;                  // [B,S,D] fp32

  short* ws     = (short*)d_ws;
  short* xb     = ws;                                    // 4096*2048
  short* Wob    = ws;                                    // 2048*2048 (alias xb;
                                                         //  converted after QKV GEMM)
  short* Wqkvb  = ws + (size_t)4096 * 2048;              // 3072*2048
  short* xqkv   = Wqkvb + (size_t)QKV_ * 2048;           // 4096*3072
  short* attn   = xqkv;                                  // 4096*2048 (alias)
  short* Qr     = xqkv + (size_t)4096 * QKV_;
  short* Kr     = Qr + (size_t)B_ * NH_ * S_ * HD_;
  short* Vv     = Kr + (size_t)B_ * NKV_ * S_ * HD_;
  short* Vtg    = Vv + (size_t)B_ * NKV_ * S_ * HD_;
  // total ~41.9M shorts = 83.9 MB (same as verified R1 layout)

  // fused convert: x (1048576 chunks) + Wqkv (786432 chunks) in one launch
  f32_to_bf16_2<<<(4096 * 2048 / 8 + QKV_ * 2048 / 8) / 256, 256, 0, stream>>>(
      x, xb, 4096 * 2048 / 8, Wqkv, Wqkvb);
  gemm_nt_bf16<QKV_, 2048, false>
      <<<dim3(QKV_ / 128, 4096 / 128), 256, 0, stream>>>(xb, Wqkvb, xqkv);
  f32_to_bf16<<<(2048 * 2048 / 8) / 256, 256, 0, stream>>>(Wo, Wob, 2048 * 2048 / 8);
  rope_split<<<(B_ * S_ * QKV_ / 8) / 256, 256, 0, stream>>>(xqkv, freqs, Qr, Kr, Vv);
  transpose_v<<<dim3(S_ / 64, HD_ / 64, B_ * NKV_), 256, 0, stream>>>(Vv, Vtg);
  attn_causal<<<dim3(32, 32), 256, 0, stream>>>(Qr, Kr, Vtg, attn);
  gemm_nt_bf16<2048, 2048, true>
      <<<dim3(2048 / 128, 4096 / 128), 256, 0, stream>>>(attn, Wob, out);
}